// Round 1
// baseline (126.283 us; speedup 1.0000x reference)
//
#include <hip/hip_runtime.h>
#include <math.h>

// MultiInterestExtractor: masked MLP-attention pooling.
//   N=8192 samples, L=200 seq, D=64 emb, A=5 hidden, K=4 heads.
//   s[n,l,k] = W2 @ tanh(W1 @ h[n,l] + b1) + b2   (masked l>=seq_len -> -inf)
//   p = softmax over l (global-max shift cancels -> per-row max is equivalent)
//   out[n,k,:] = sum_l p[n,k,l] * h[n,l,:]
//
// One block (256 thr = 4 waves) per sample. Only rows l < seq_len are ever
// fetched from HBM (~50% of input on average). LDS row stride 65 makes all
// staging-write / row-read / column-read patterns 2-way (free) on 32 banks.

#define LL 200
#define DD 64
#define AA 5
#define KK 4
#define HSTRIDE 65   // 200*65*4 = 52000 B

__global__ __launch_bounds__(256, 2)
void mie_kernel(const float* __restrict__ h_g,    // [N, L, D]
                const int*   __restrict__ slen_g, // [N]
                const float* __restrict__ W1w,    // [A, D]
                const float* __restrict__ W1b,    // [A]
                const float* __restrict__ W2w,    // [K, A]
                const float* __restrict__ W2b,    // [K]
                float*       __restrict__ out)    // [N, K, D]
{
    __shared__ float h_lds[LL * HSTRIDE];                  // 52000 B
    __shared__ float s_lds[KK][LL];                        //  3200 B
    __shared__ __align__(16) float p_lds[LL][KK];          //  3200 B (l-major for float4 reads)
    __shared__ float part[4][KK][DD];                      //  4096 B

    const int n    = blockIdx.x;
    const int t    = threadIdx.x;
    const int lane = t & 63;
    const int wave = t >> 6;
    const int slen = slen_g[n];

    // ---- stage valid rows into LDS: coalesced float4 global loads ----
    const float4* hn4 = (const float4*)(h_g + (size_t)n * LL * DD);
    const int nf4 = slen * (DD / 4);
    for (int i = t; i < nf4; i += 256) {
        float4 v = hn4[i];
        int l  = i >> 4;            // i / 16
        int d0 = (i & 15) << 2;
        float* dst = &h_lds[l * HSTRIDE + d0];
        dst[0] = v.x; dst[1] = v.y; dst[2] = v.z; dst[3] = v.w;
    }
    __syncthreads();

    // ---- score pass: thread t = position l. W1/W2 indices are wave-uniform
    //      -> compiler emits s_load (scalar pipe), no per-lane traffic. ----
    if (t < LL) {
        const int l = t;
        float sk[KK];
        if (l < slen) {
            float acc[AA];
            #pragma unroll
            for (int a = 0; a < AA; ++a) acc[a] = W1b[a];
            const float* hrow = &h_lds[l * HSTRIDE];
            #pragma unroll 8
            for (int d = 0; d < DD; ++d) {
                float hv = hrow[d];
                #pragma unroll
                for (int a = 0; a < AA; ++a)
                    acc[a] = fmaf(hv, W1w[a * DD + d], acc[a]);
            }
            float ta[AA];
            #pragma unroll
            for (int a = 0; a < AA; ++a) ta[a] = tanhf(acc[a]);
            #pragma unroll
            for (int k = 0; k < KK; ++k) {
                float s = W2b[k];
                #pragma unroll
                for (int a = 0; a < AA; ++a)
                    s = fmaf(ta[a], W2w[k * AA + a], s);
                sk[k] = s;
            }
        } else {
            #pragma unroll
            for (int k = 0; k < KK; ++k) sk[k] = -INFINITY;
        }
        #pragma unroll
        for (int k = 0; k < KK; ++k) s_lds[k][l] = sk[k];
    }
    __syncthreads();

    // ---- softmax over l: wave w owns head k = w (per-row max; shift-
    //      invariance makes this identical to the reference's global max) ----
    {
        const int k = wave;
        float v[4];
        #pragma unroll
        for (int c = 0; c < 4; ++c) {
            int l = lane + 64 * c;
            v[c] = (l < LL) ? s_lds[k][l] : -INFINITY;
        }
        float m = fmaxf(fmaxf(v[0], v[1]), fmaxf(v[2], v[3]));
        #pragma unroll
        for (int off = 32; off > 0; off >>= 1)
            m = fmaxf(m, __shfl_xor(m, off, 64));
        float e[4];
        float sum = 0.f;
        #pragma unroll
        for (int c = 0; c < 4; ++c) {
            e[c] = expf(v[c] - m);      // exp(-inf) = 0 for masked/padded
            sum += e[c];
        }
        #pragma unroll
        for (int off = 32; off > 0; off >>= 1)
            sum += __shfl_xor(sum, off, 64);
        const float inv = 1.0f / sum;   // sum >= 1 (seq_len >= 1)
        #pragma unroll
        for (int c = 0; c < 4; ++c) {
            int l = lane + 64 * c;
            if (l < LL) p_lds[l][k] = e[c] * inv;
        }
    }
    __syncthreads();

    // ---- PV: wave w handles l-quarter, all 4 heads per thread (each h
    //      element read from LDS exactly once). ----
    {
        const int q  = (slen + 3) >> 2;
        const int l0 = wave * q;
        const int l1 = min(l0 + q, slen);
        const int dd = lane;
        float acc0 = 0.f, acc1 = 0.f, acc2 = 0.f, acc3 = 0.f;
        for (int l = l0; l < l1; ++l) {
            float  hv = h_lds[l * HSTRIDE + dd];
            float4 p4 = *(const float4*)&p_lds[l][0];
            acc0 = fmaf(p4.x, hv, acc0);
            acc1 = fmaf(p4.y, hv, acc1);
            acc2 = fmaf(p4.z, hv, acc2);
            acc3 = fmaf(p4.w, hv, acc3);
        }
        part[wave][0][dd] = acc0;
        part[wave][1][dd] = acc1;
        part[wave][2][dd] = acc2;
        part[wave][3][dd] = acc3;
    }
    __syncthreads();

    // ---- cross-wave reduce + coalesced store ----
    {
        const int k  = t >> 6;
        const int dd = t & 63;
        float r = part[0][k][dd] + part[1][k][dd] + part[2][k][dd] + part[3][k][dd];
        out[(size_t)n * (KK * DD) + t] = r;
    }
}

extern "C" void kernel_launch(void* const* d_in, const int* in_sizes, int n_in,
                              void* d_out, int out_size, void* d_ws, size_t ws_size,
                              hipStream_t stream) {
    const float* h_g    = (const float*)d_in[0];
    const int*   slen   = (const int*)  d_in[1];
    const float* W1w    = (const float*)d_in[2];
    const float* W1b    = (const float*)d_in[3];
    const float* W2w    = (const float*)d_in[4];
    const float* W2b    = (const float*)d_in[5];
    float*       outp   = (float*)d_out;

    const int N = in_sizes[1];   // pratical_seq_len has N elements

    mie_kernel<<<dim3(N), dim3(256), 0, stream>>>(h_g, slen, W1w, W1b, W2w, W2b, outp);
}